// Round 2
// baseline (479.041 us; speedup 1.0000x reference)
//
#include <hip/hip_runtime.h>
#include <hip/hip_bf16.h>

#define NGRAPH 16384
#define NPG    9
#define DM     128
#define NLAY   4
#define EPG    16
#define GPB    14
#define RPB    128
#define NBLK   1171   /* ceil(16384/14) */

typedef __attribute__((ext_vector_type(8))) short bf16x8;
typedef __attribute__((ext_vector_type(4))) float f32x4;

__device__ __forceinline__ float b2f(unsigned short u){
  union { unsigned int i; float f; } v; v.i = ((unsigned int)u) << 16; return v.f;
}
__device__ __forceinline__ unsigned short f2b(float f){
  union { float fv; unsigned int i; } v; v.fv = f;
  unsigned int r = v.i + 0x7FFFu + ((v.i >> 16) & 1u);
  return (unsigned short)(r >> 16);
}

struct Stg { f32x4 r[8]; };

__device__ __forceinline__ void stg_issue(Stg& s, const unsigned short* src, int tid){
  const f32x4* g = (const f32x4*)src;
  #pragma unroll
  for (int i = 0; i < 8; ++i) s.r[i] = g[i*256 + tid];
}
__device__ __forceinline__ void stg_write(const Stg& s, unsigned short* dst, int tid){
  f32x4* d = (f32x4*)dst;
  #pragma unroll
  for (int i = 0; i < 8; ++i) d[i*256 + tid] = s.r[i];
}

__device__ __forceinline__ bf16x8 ldfrag(const unsigned short* buf, int row, int kk, int g16){
  return *(const bf16x8*)&buf[row*DM + ((kk*32 + g16*8) ^ ((row & 7) << 3))];
}
__device__ __forceinline__ f32x4 mfma16(bf16x8 a, bf16x8 b, f32x4 c){
  return __builtin_amdgcn_mfma_f32_16x16x32_bf16(a, b, c, 0, 0, 0);
}

// Pre-transpose + convert f32->bf16 + swizzle weights into workspace:
// tiles (16384 bf16 each): per layer l: [0]=WgT, [1..4]=W1T chunk c (cols 128c..),
// [5..8]=W2T chunk c (k-rows 128c..). Element (n,k) stored at n*128 + (k ^ ((n&7)<<3)).
__global__ void wtr_kernel(const float* __restrict__ Wg,
                           const float* __restrict__ W1,
                           const float* __restrict__ W2,
                           unsigned short* __restrict__ wsT){
  int t = blockIdx.x * 256 + threadIdx.x;
  int tile = t >> 14;
  int e = t & 16383;
  int k = e >> 7;
  int n = e & 127;
  int l = tile / 9, t9 = tile - l*9;
  float v;
  if (t9 == 0)      v = Wg[l*16384 + k*128 + n];
  else if (t9 < 5)  v = W1[l*65536 + k*512 + (t9-1)*128 + n];
  else              v = W2[l*65536 + ((t9-5)*128 + k)*128 + n];
  wsT[tile*16384 + n*128 + (k ^ ((n & 7) << 3))] = f2b(v);
}

__global__ void __launch_bounds__(256, 1)
gcn_kernel(const float* __restrict__ op_table,
           const float* __restrict__ dev_emb,
           const float* __restrict__ bgp,
           const float* __restrict__ lngp,
           const float* __restrict__ lnbp,
           const float* __restrict__ b1p,
           const float* __restrict__ b2p,
           const float* __restrict__ fcw,
           const float* __restrict__ fcb,
           const int* __restrict__ op_idx,
           const int* __restrict__ srcA,
           const int* __restrict__ dstA,
           const unsigned short* __restrict__ wsT,
           float* __restrict__ out)
{
  __shared__ unsigned short hbuf[RPB*DM];      // natural h; aliased as swizzled H-chunk in FFN
  __shared__ unsigned short Abuf[RPB*DM];      // swizzled A operand (agg, then X)
  __shared__ unsigned short Wbuf[2][DM*DM];    // double-buffered weight tile
  __shared__ float cntF[GPB][81];
  __shared__ float isd_s[RPB];
  __shared__ float bg_s[DM], lng_s[DM], lnb_s[DM], b2_s[DM];
  __shared__ float b1_s[4*DM];

  const int tid  = threadIdx.x;
  const int w    = tid >> 6;
  const int lane = tid & 63;
  const int g16  = lane >> 4;
  const int l15  = lane & 15;
  const int rbase = w * 32;
  const int g0 = blockIdx.x * GPB;
  const int nvalid = (NGRAPH - g0 < GPB) ? (NGRAPH - g0) : GPB;

  // ---------------- preamble ----------------
  for (int i = tid; i < GPB*81; i += 256) (&cntF[0][0])[i] = 0.f;

  { // h0 = op_table[idx] + device_emb (f32 -> bf16) ; zeros for pad/invalid rows
    int r  = tid >> 1;
    int fh = (tid & 1) * 64;
    int gi = r / NPG;
    int j  = r - gi*NPG;
    bf16x8* dstp = (bf16x8*)&hbuf[r*DM + fh];
    if (r < GPB*NPG && gi < nvalid) {
      int idx = op_idx[(g0 + gi)*NPG + j];
      const float4* ot = (const float4*)&op_table[idx*DM + fh];
      const float4* de = (const float4*)&dev_emb[fh];
      #pragma unroll
      for (int i = 0; i < 8; ++i){
        float4 a0 = ot[2*i], a1 = ot[2*i+1];
        float4 d0 = de[2*i], d1 = de[2*i+1];
        bf16x8 o;
        o[0] = (short)f2b(a0.x + d0.x); o[1] = (short)f2b(a0.y + d0.y);
        o[2] = (short)f2b(a0.z + d0.z); o[3] = (short)f2b(a0.w + d0.w);
        o[4] = (short)f2b(a1.x + d1.x); o[5] = (short)f2b(a1.y + d1.y);
        o[6] = (short)f2b(a1.z + d1.z); o[7] = (short)f2b(a1.w + d1.w);
        dstp[i] = o;
      }
    } else {
      bf16x8 z;
      #pragma unroll
      for (int q = 0; q < 8; ++q) z[q] = 0;
      #pragma unroll
      for (int i = 0; i < 8; ++i) dstp[i] = z;
    }
  }
  __syncthreads();

  if (tid < GPB && tid < nvalid) { // per-graph 9x9 count matrix (incl. self loops)
    float* c = cntF[tid];
    for (int e = 0; e < EPG; ++e){
      int s = srcA[(g0 + tid)*EPG + e];
      int d = dstA[(g0 + tid)*EPG + e];
      c[(s % NPG)*NPG + (d % NPG)] += 1.f;
    }
    #pragma unroll
    for (int j = 0; j < NPG; ++j) c[j*NPG + j] += 1.f;
  }
  __syncthreads();

  if (tid < RPB) { // deg = column sums of cnt ; isd = rsqrt(deg)  (deg>=1 via self loop)
    int gi = tid / NPG;
    if (tid < GPB*NPG && gi < nvalid) {
      int jd = tid - gi*NPG;
      float s = 0.f;
      #pragma unroll
      for (int js = 0; js < NPG; ++js) s += cntF[gi][js*NPG + jd];
      isd_s[tid] = rsqrtf(s);
    } else isd_s[tid] = 1.f;
  }
  { // stage Wg[0] into Wbuf[0]
    Stg s0;
    stg_issue(s0, wsT, tid);
    stg_write(s0, Wbuf[0], tid);
  }
  __syncthreads();

  f32x4 Xres[2][8];
  Stg sA, sB;

  #pragma unroll 1
  for (int l = 0; l < NLAY; ++l){
    // ---------- Phase A: aggregation -> Abuf ----------
    if (l > 0) stg_write(sB, Wbuf[0], tid);          // Wg[l] (issued at prev layer c==3)
    stg_issue(sA, wsT + (l*9 + 1)*16384, tid);       // W1 chunk 0
    if (tid < DM) {
      bg_s[tid]  = bgp [l*DM + tid];
      lng_s[tid] = lngp[l*DM + tid];
      lnb_s[tid] = lnbp[l*DM + tid];
      b2_s[tid]  = b2p [l*DM + tid];
    }
    b1_s[tid]       = b1p[l*4*DM + tid];
    b1_s[tid + 256] = b1p[l*4*DM + 256 + tid];
    {
      int gi = tid >> 4;
      int f0 = (tid & 15) * 8;
      if (gi < GPB) {
        float hs[NPG][8];
        #pragma unroll
        for (int j = 0; j < NPG; ++j){
          int row = gi*NPG + j;
          bf16x8 hv = *(const bf16x8*)&hbuf[row*DM + f0];
          float is = isd_s[row];
          #pragma unroll
          for (int i = 0; i < 8; ++i) hs[j][i] = b2f((unsigned short)hv[i]) * is;
        }
        #pragma unroll
        for (int jd = 0; jd < NPG; ++jd){
          float av[8];
          #pragma unroll
          for (int i = 0; i < 8; ++i) av[i] = 0.f;
          #pragma unroll
          for (int js = 0; js < NPG; ++js){
            float cc = cntF[gi][js*NPG + jd];
            #pragma unroll
            for (int i = 0; i < 8; ++i) av[i] = fmaf(cc, hs[js][i], av[i]);
          }
          int row = gi*NPG + jd;
          float is = isd_s[row];
          bf16x8 o;
          #pragma unroll
          for (int i = 0; i < 8; ++i) o[i] = (short)f2b(av[i] * is);
          *(bf16x8*)&Abuf[row*DM + (f0 ^ ((row & 7) << 3))] = o;
        }
      } else { // zero pad rows 126,127 (write all 16 segs -> whole rows zero)
        int k2 = tid - 224;
        int row = 126 + (k2 >> 4);
        int seg = (k2 & 15) * 8;
        bf16x8 z;
        #pragma unroll
        for (int q = 0; q < 8; ++q) z[q] = 0;
        *(bf16x8*)&Abuf[row*DM + seg] = z;
      }
    }
    stg_write(sA, Wbuf[1], tid);                     // W1 chunk 0 -> buf1
    __syncthreads();

    // ---------- Phase B: X = LN(relu(agg @ Wg + bg)) ----------
    stg_issue(sB, wsT + (l*9 + 5)*16384, tid);       // W2 chunk 0
    f32x4 acc[2][8];
    #pragma unroll
    for (int mt = 0; mt < 2; ++mt)
      #pragma unroll
      for (int nt = 0; nt < 8; ++nt){ f32x4 z; z[0]=z[1]=z[2]=z[3]=0.f; acc[mt][nt]=z; }
    #pragma unroll
    for (int kk = 0; kk < 4; ++kk){
      bf16x8 a0 = ldfrag(Abuf, rbase + l15, kk, g16);
      bf16x8 a1 = ldfrag(Abuf, rbase + 16 + l15, kk, g16);
      #pragma unroll
      for (int nt = 0; nt < 8; ++nt){
        bf16x8 bb = ldfrag(Wbuf[0], nt*16 + l15, kk, g16);
        acc[0][nt] = mfma16(a0, bb, acc[0][nt]);
        acc[1][nt] = mfma16(a1, bb, acc[1][nt]);
      }
    }
    #pragma unroll
    for (int mt = 0; mt < 2; ++mt){
      float rs[4], rq[4];
      #pragma unroll
      for (int j = 0; j < 4; ++j){ rs[j] = 0.f; rq[j] = 0.f; }
      #pragma unroll
      for (int nt = 0; nt < 8; ++nt){
        #pragma unroll
        for (int j = 0; j < 4; ++j){
          float v = acc[mt][nt][j] + bg_s[nt*16 + l15];
          v = fmaxf(v, 0.f);
          acc[mt][nt][j] = v;
          rs[j] += v; rq[j] += v*v;
        }
      }
      #pragma unroll
      for (int j = 0; j < 4; ++j){
        #pragma unroll
        for (int mm = 1; mm < 16; mm <<= 1){
          rs[j] += __shfl_xor(rs[j], mm, 64);
          rq[j] += __shfl_xor(rq[j], mm, 64);
        }
        float mu  = rs[j] * (1.f/128.f);
        float var = rq[j] * (1.f/128.f) - mu*mu;
        rs[j] = mu;
        rq[j] = rsqrtf(var + 1e-5f);
      }
      int rowb = rbase + mt*16 + g16*4;
      #pragma unroll
      for (int nt = 0; nt < 8; ++nt){
        int col = nt*16 + l15;
        float lg = lng_s[col], lb = lnb_s[col];
        #pragma unroll
        for (int j = 0; j < 4; ++j){
          float x = (acc[mt][nt][j] - rs[j]) * rq[j] * lg + lb;
          Xres[mt][nt][j] = x;
          int row = rowb + j;
          Abuf[row*DM + (col ^ ((row & 7) << 3))] = f2b(x);
        }
      }
    }
    __syncthreads();

    // ---------- FFN in 4 chunks of 128 ----------
    f32x4 c2[2][8];
    #pragma unroll
    for (int mt = 0; mt < 2; ++mt)
      #pragma unroll
      for (int nt = 0; nt < 8; ++nt){ f32x4 z; z[0]=z[1]=z[2]=z[3]=0.f; c2[mt][nt]=z; }
    #pragma unroll
    for (int c = 0; c < 4; ++c){
      stg_write(sB, Wbuf[0], tid);                                  // W2 chunk c
      if (c < 3)      stg_issue(sA, wsT + (l*9 + 2 + c)*16384, tid); // W1 chunk c+1
      else if (l < 3) stg_issue(sB, wsT + ((l+1)*9)*16384, tid);     // Wg[l+1]

      // FFN1: Hc = relu(X @ W1c + b1c) -> hbuf (swizzled, own rows)
      f32x4 hc[2][8];
      #pragma unroll
      for (int mt = 0; mt < 2; ++mt)
        #pragma unroll
        for (int nt = 0; nt < 8; ++nt){ f32x4 z; z[0]=z[1]=z[2]=z[3]=0.f; hc[mt][nt]=z; }
      #pragma unroll
      for (int kk = 0; kk < 4; ++kk){
        bf16x8 a0 = ldfrag(Abuf, rbase + l15, kk, g16);
        bf16x8 a1 = ldfrag(Abuf, rbase + 16 + l15, kk, g16);
        #pragma unroll
        for (int nt = 0; nt < 8; ++nt){
          bf16x8 bb = ldfrag(Wbuf[1], nt*16 + l15, kk, g16);
          hc[0][nt] = mfma16(a0, bb, hc[0][nt]);
          hc[1][nt] = mfma16(a1, bb, hc[1][nt]);
        }
      }
      #pragma unroll
      for (int mt = 0; mt < 2; ++mt){
        int rowb = rbase + mt*16 + g16*4;
        #pragma unroll
        for (int nt = 0; nt < 8; ++nt){
          int col = nt*16 + l15;
          float bv = b1_s[c*128 + col];
          #pragma unroll
          for (int j = 0; j < 4; ++j){
            float v = fmaxf(hc[mt][nt][j] + bv, 0.f);
            int row = rowb + j;
            hbuf[row*DM + (col ^ ((row & 7) << 3))] = f2b(v);
          }
        }
      }
      __syncthreads();

      if (c < 3){ stg_write(sA, Wbuf[1], tid); stg_issue(sB, wsT + (l*9 + 6 + c)*16384, tid); }

      // FFN2: c2 += Hc @ W2c
      #pragma unroll
      for (int kk = 0; kk < 4; ++kk){
        bf16x8 a0 = ldfrag(hbuf, rbase + l15, kk, g16);
        bf16x8 a1 = ldfrag(hbuf, rbase + 16 + l15, kk, g16);
        #pragma unroll
        for (int nt = 0; nt < 8; ++nt){
          bf16x8 bb = ldfrag(Wbuf[0], nt*16 + l15, kk, g16);
          c2[0][nt] = mfma16(a0, bb, c2[0][nt]);
          c2[1][nt] = mfma16(a1, bb, c2[1][nt]);
        }
      }
      __syncthreads();
    }

    // ---------- Phase D: h = X + c2 + b2 ----------
    #pragma unroll
    for (int mt = 0; mt < 2; ++mt){
      int rowb = rbase + mt*16 + g16*4;
      #pragma unroll
      for (int nt = 0; nt < 8; ++nt){
        int col = nt*16 + l15;
        float b2v = b2_s[col];
        #pragma unroll
        for (int j = 0; j < 4; ++j){
          int row = rowb + j;
          hbuf[row*DM + col] = f2b(Xres[mt][nt][j] + c2[mt][nt][j] + b2v);
        }
      }
    }
    __syncthreads();
  }

  // ---------------- readout ----------------
  {
    int gi = tid >> 4;
    int f0 = (tid & 15) * 8;
    if (gi < nvalid) {
      float m[8];
      #pragma unroll
      for (int i = 0; i < 8; ++i) m[i] = 0.f;
      #pragma unroll
      for (int j = 0; j < NPG; ++j){
        bf16x8 hv = *(const bf16x8*)&hbuf[(gi*NPG + j)*DM + f0];
        #pragma unroll
        for (int i = 0; i < 8; ++i) m[i] += b2f((unsigned short)hv[i]);
      }
      const float4* fw = (const float4*)&fcw[f0];
      float4 w0 = fw[0], w1 = fw[1];
      float dot = m[0]*w0.x + m[1]*w0.y + m[2]*w0.z + m[3]*w0.w
                + m[4]*w1.x + m[5]*w1.y + m[6]*w1.z + m[7]*w1.w;
      dot *= (1.f/9.f);
      #pragma unroll
      for (int mm = 1; mm < 16; mm <<= 1) dot += __shfl_xor(dot, mm, 64);
      if ((tid & 15) == 0){
        float z = dot + fcb[0];
        out[g0 + gi] = 1.f / (1.f + __expf(-z));
      }
    }
  }
}

extern "C" void kernel_launch(void* const* d_in, const int* in_sizes, int n_in,
                              void* d_out, int out_size, void* d_ws, size_t ws_size,
                              hipStream_t stream)
{
  const float* op_table = (const float*)d_in[0];
  const float* dev_emb  = (const float*)d_in[1];
  const float* Wg  = (const float*)d_in[2];
  const float* bg  = (const float*)d_in[3];
  const float* lng = (const float*)d_in[4];
  const float* lnb = (const float*)d_in[5];
  const float* W1  = (const float*)d_in[6];
  const float* b1  = (const float*)d_in[7];
  const float* W2  = (const float*)d_in[8];
  const float* b2  = (const float*)d_in[9];
  const float* fcw = (const float*)d_in[10];
  const float* fcb = (const float*)d_in[11];
  const int* op_idx = (const int*)d_in[12];
  const int* srcA   = (const int*)d_in[13];
  const int* dstA   = (const int*)d_in[14];
  unsigned short* wsT = (unsigned short*)d_ws;

  wtr_kernel<<<2304, 256, 0, stream>>>(Wg, W1, W2, wsT);
  gcn_kernel<<<NBLK, 256, 0, stream>>>(op_table, dev_emb, bg, lng, lnb, b1, b2,
                                       fcw, fcb, op_idx, srcA, dstA, wsT,
                                       (float*)d_out);
}